// Round 7
// baseline (350.853 us; speedup 1.0000x reference)
//
#include <hip/hip_runtime.h>
#include <hip/hip_bf16.h>
#include <cstdint>
#include <cstddef>

// Graph Transformer: 2x TransformerConv (H=8) + Linear(8,100) + mean over nodes.
// Round 7: CSR build restructured — rank_edges (atomic count WITH rank return,
// u16 ranks) + single-block scan + atomic-free place_edges (u16 srcs).
// Dispatches 16 -> 9 (memsets folded into pack_weights, 3 scans -> 1).
// Layouts:
//   qs[N,256]    fp16: [ q(128, pre-scaled by 0.25) | s(128) ]
//   kvbuf[N,256] fp8 : [ (k2c,k2c+1,v2c,v2c+1) x64 ]   (256B gather row)
//   qkvs2[N,32]  fp16: [ q(8) | (k_h,v_h) x8 | s(8) ]

typedef _Float16 f16x8 __attribute__((ext_vector_type(8)));
typedef _Float16 f16x4 __attribute__((ext_vector_type(4)));
typedef _Float16 f16x2 __attribute__((ext_vector_type(2)));
typedef float    f32x4 __attribute__((ext_vector_type(4)));
typedef float    f32x2 __attribute__((ext_vector_type(2)));

// ---------------- weight packing + zero-init (counts, out) ----------------
__global__ __launch_bounds__(256) void pack_weights(
    const float* __restrict__ Wq1, const float* __restrict__ bq1,
    const float* __restrict__ Wk1, const float* __restrict__ bk1,
    const float* __restrict__ Wv1, const float* __restrict__ bv1,
    const float* __restrict__ Ws1, const float* __restrict__ bs1,
    const float* __restrict__ Wq2, const float* __restrict__ bq2,
    const float* __restrict__ Wk2, const float* __restrict__ bk2,
    const float* __restrict__ Wv2, const float* __restrict__ bv2,
    const float* __restrict__ Ws2, const float* __restrict__ bs2,
    _Float16* __restrict__ Wt1, float* __restrict__ b1,
    _Float16* __restrict__ Wt2, float* __restrict__ b2,
    int* __restrict__ counts, float* __restrict__ out, int n, int out_size)
{
    int i = blockIdx.x * 256 + threadIdx.x;
    if (i < n) counts[i] = 0;
    if (i < out_size) out[i] = 0.f;
    if (i < 65536) {                       // Wt1[j][k]
        int j = i >> 7, k = i & 127;
        const float* W; int col; float sc = 1.f;
        if (j < 128)      { W = Wq1; col = j; sc = 0.25f; }   // fold 1/sqrt(16)
        else if (j < 384) { int t = j - 128, c = t >> 2, r = t & 3;
                            if (r < 2) { W = Wk1; col = 2 * c + r; }
                            else       { W = Wv1; col = 2 * c + r - 2; } }
        else              { W = Ws1; col = j - 384; }
        Wt1[i] = (_Float16)(W[k * 128 + col] * sc);
    } else if (i < 66048) {
        int j = i - 65536;
        const float* B; int col; float sc = 1.f;
        if (j < 128)      { B = bq1; col = j; sc = 0.25f; }
        else if (j < 384) { int t = j - 128, c = t >> 2, r = t & 3;
                            if (r < 2) { B = bk1; col = 2 * c + r; }
                            else       { B = bv1; col = 2 * c + r - 2; } }
        else              { B = bs1; col = j - 384; }
        b1[j] = B[col] * sc;
    } else if (i < 66048 + 4096) {         // Wt2[j][k]
        int t = i - 66048;
        int j = t >> 7, k = t & 127;
        const float* W; int col;
        if (j < 8)       { W = Wq2; col = j; }
        else if (j < 24) { int u = j - 8; col = u >> 1; W = (u & 1) ? Wv2 : Wk2; }
        else             { W = Ws2; col = j - 24; }
        Wt2[t] = (_Float16)W[k * 8 + col];
    } else if (i < 66048 + 4096 + 32) {
        int j = i - (66048 + 4096);
        const float* B; int col;
        if (j < 8)       { B = bq2; col = j; }
        else if (j < 24) { int u = j - 8; col = u >> 1; B = (u & 1) ? bv2 : bk2; }
        else             { B = bs2; col = j - 24; }
        b2[j] = B[col];
    }
}

// ---------------- rank_edges: count + per-edge rank (4 edges/thread) ----------------
__global__ __launch_bounds__(256) void rank_edges(
    const int* __restrict__ ei, int* __restrict__ counts,
    unsigned short* __restrict__ rank, int E)
{
    int e0 = (blockIdx.x * 256 + threadIdx.x) * 4;
    if (e0 + 4 <= E) {
        int4 d4 = *(const int4*)&ei[E + e0];
        int r0 = atomicAdd(&counts[d4.x], 1);
        int r1 = atomicAdd(&counts[d4.y], 1);
        int r2 = atomicAdd(&counts[d4.z], 1);
        int r3 = atomicAdd(&counts[d4.w], 1);
        ushort4 rr = make_ushort4((unsigned short)r0, (unsigned short)r1,
                                  (unsigned short)r2, (unsigned short)r3);
        *(ushort4*)&rank[e0] = rr;
    } else {
        for (int e = e0; e < E; ++e)
            rank[e] = (unsigned short)atomicAdd(&counts[ei[E + e]], 1);
    }
}

// ---------------- scan_all: single-block exclusive scan of counts -> indptr ----------------
__global__ __launch_bounds__(1024) void scan_all(
    const int* __restrict__ counts, int* __restrict__ indptr, int n, int E)
{
    int t = threadIdx.x, lane = t & 63;
    int per = (n + 1023) / 1024;
    int lo = t * per, hi = min(n, lo + per);
    int s = 0;
    for (int i = lo; i < hi; ++i) s += counts[i];
    int x = s;
    #pragma unroll
    for (int off = 1; off < 64; off <<= 1) {
        int y = __shfl_up(x, off, 64);
        if (lane >= off) x += y;
    }
    __shared__ int ws[16];
    if (lane == 63) ws[t >> 6] = x;
    __syncthreads();
    int woff = 0;
    for (int w = 0; w < (t >> 6); ++w) woff += ws[w];
    int run = woff + x - s;                // exclusive prefix of this chunk
    for (int i = lo; i < hi; ++i) { indptr[i] = run; run += counts[i]; }
    if (t == 0) indptr[n] = E;
}

// ---------------- place_edges: atomic-free scatter (u16 srcs) ----------------
__global__ __launch_bounds__(256) void place_edges(
    const int* __restrict__ ei, const int* __restrict__ indptr,
    const unsigned short* __restrict__ rank, unsigned short* __restrict__ srcs, int E)
{
    int e0 = (blockIdx.x * 256 + threadIdx.x) * 4;
    if (e0 + 4 <= E) {
        int4 s4 = *(const int4*)&ei[e0];
        int4 d4 = *(const int4*)&ei[E + e0];
        ushort4 r4 = *(const ushort4*)&rank[e0];
        srcs[indptr[d4.x] + r4.x] = (unsigned short)s4.x;
        srcs[indptr[d4.y] + r4.y] = (unsigned short)s4.y;
        srcs[indptr[d4.z] + r4.z] = (unsigned short)s4.z;
        srcs[indptr[d4.w] + r4.w] = (unsigned short)s4.w;
    } else {
        for (int e = e0; e < E; ++e)
            srcs[indptr[ei[E + e]] + rank[e]] = (unsigned short)ei[e];
    }
}

// ---------------- gemm1: col-loop, A staged once, Bs/Ds LDS union ----------------
__global__ __launch_bounds__(256) void gemm1(
    const float* __restrict__ x, const _Float16* __restrict__ Wt1,
    const float* __restrict__ b1, _Float16* __restrict__ qs,
    unsigned char* __restrict__ kvbuf, int n)
{
    __shared__ _Float16 As[64][136];
    __shared__ _Float16 BD[64][136];   // Bs during MFMA, Ds during epilogue
    int tid = threadIdx.x;
    int rowbase = blockIdx.x * 64;
    #pragma unroll
    for (int it = 0; it < 8; ++it) {   // A: fp32 load + convert, 64x128
        int c = it * 256 + tid, row = c >> 5, ch = c & 31;
        float4 v = make_float4(0.f, 0.f, 0.f, 0.f);
        if (rowbase + row < n) v = *(const float4*)&x[(size_t)(rowbase + row) * 128 + ch * 4];
        f16x4 hv = { (_Float16)v.x, (_Float16)v.y, (_Float16)v.z, (_Float16)v.w };
        *(f16x4*)&As[row][ch * 4] = hv;
    }
    int w = tid >> 6, l = tid & 63;
    int wm = w >> 1, wn = w & 1, fr = l & 15, fg = l >> 4;
    for (int cb = 0; cb < 8; ++cb) {
        __syncthreads();               // As ready / previous Ds consumed
        #pragma unroll
        for (int it = 0; it < 4; ++it) {
            int c = it * 256 + tid, row = c >> 4, ch = c & 15;
            *(f16x8*)&BD[row][ch * 8] =
                *(const f16x8*)&Wt1[(size_t)(cb * 64 + row) * 128 + ch * 8];
        }
        __syncthreads();
        f32x4 acc[2][2] = {};
        #pragma unroll
        for (int kk = 0; kk < 4; ++kk) {
            int ko = kk * 32 + fg * 8;
            f16x8 a0 = *(const f16x8*)&As[wm * 32 + fr][ko];
            f16x8 a1 = *(const f16x8*)&As[wm * 32 + 16 + fr][ko];
            f16x8 b0 = *(const f16x8*)&BD[wn * 32 + fr][ko];
            f16x8 b1v = *(const f16x8*)&BD[wn * 32 + 16 + fr][ko];
            acc[0][0] = __builtin_amdgcn_mfma_f32_16x16x32_f16(a0, b0, acc[0][0], 0, 0, 0);
            acc[0][1] = __builtin_amdgcn_mfma_f32_16x16x32_f16(a0, b1v, acc[0][1], 0, 0, 0);
            acc[1][0] = __builtin_amdgcn_mfma_f32_16x16x32_f16(a1, b0, acc[1][0], 0, 0, 0);
            acc[1][1] = __builtin_amdgcn_mfma_f32_16x16x32_f16(a1, b1v, acc[1][1], 0, 0, 0);
        }
        __syncthreads();               // Bs reads done; BD becomes Ds
        #pragma unroll
        for (int nt = 0; nt < 2; ++nt) {   // C/D: col=lane&15, row=(lane>>4)*4+r (m89)
            int col = wn * 32 + nt * 16 + fr;
            float bv = b1[cb * 64 + col];
            #pragma unroll
            for (int mt = 0; mt < 2; ++mt)
                #pragma unroll
                for (int r = 0; r < 4; ++r)
                    BD[wm * 32 + mt * 16 + fg * 4 + r][col] = (_Float16)(acc[mt][nt][r] + bv);
        }
        __syncthreads();
        if (cb >= 2 && cb < 6) {       // kv cols -> fp8 pack, 64 rows x 64 bytes
            int row = tid >> 2, ch = tid & 3;
            if (rowbase + row < n) {
                f16x8 d0 = *(const f16x8*)&BD[row][ch * 16];
                f16x8 d1 = *(const f16x8*)&BD[row][ch * 16 + 8];
                int w0 = 0, w1 = 0, w2 = 0, w3 = 0;
                w0 = __builtin_amdgcn_cvt_pk_fp8_f32((float)d0[0], (float)d0[1], w0, false);
                w0 = __builtin_amdgcn_cvt_pk_fp8_f32((float)d0[2], (float)d0[3], w0, true);
                w1 = __builtin_amdgcn_cvt_pk_fp8_f32((float)d0[4], (float)d0[5], w1, false);
                w1 = __builtin_amdgcn_cvt_pk_fp8_f32((float)d0[6], (float)d0[7], w1, true);
                w2 = __builtin_amdgcn_cvt_pk_fp8_f32((float)d1[0], (float)d1[1], w2, false);
                w2 = __builtin_amdgcn_cvt_pk_fp8_f32((float)d1[2], (float)d1[3], w2, true);
                w3 = __builtin_amdgcn_cvt_pk_fp8_f32((float)d1[4], (float)d1[5], w3, false);
                w3 = __builtin_amdgcn_cvt_pk_fp8_f32((float)d1[6], (float)d1[7], w3, true);
                uint4 o = make_uint4((unsigned)w0, (unsigned)w1, (unsigned)w2, (unsigned)w3);
                *(uint4*)&kvbuf[(size_t)(rowbase + row) * 256 + (cb - 2) * 64 + ch * 16] = o;
            }
        } else {                       // q / s cols -> qs fp16
            int dcol = (cb < 2) ? cb * 64 : (cb - 6) * 64 + 128;
            #pragma unroll
            for (int it = 0; it < 2; ++it) {
                int c = it * 256 + tid, row = c >> 3, ch = c & 7;
                if (rowbase + row < n)
                    *(f16x8*)&qs[(size_t)(rowbase + row) * 256 + dcol + ch * 8] =
                        *(const f16x8*)&BD[row][ch * 8];
            }
        }
    }
}

// ---------------- attn1: quarter-wave per edge, fp8 kv, no-max softmax ----------------
__global__ __launch_bounds__(256) void attn1(
    const _Float16* __restrict__ qs, const unsigned char* __restrict__ kvbuf,
    const int* __restrict__ indptr, const unsigned short* __restrict__ srcs,
    _Float16* __restrict__ h1, int n)
{
    int wid = threadIdx.x >> 6, l = threadIdx.x & 63;
    int node = blockIdx.x * 4 + wid;
    if (node >= n) return;
    int lam = l & 15, quarter = l >> 4;
    const _Float16* nrow = qs + (size_t)node * 256;
    f16x8 q8 = ((const f16x8*)nrow)[lam];
    float qf0 = (float)q8[0], qf1 = (float)q8[1], qf2 = (float)q8[2], qf3 = (float)q8[3];
    float qf4 = (float)q8[4], qf5 = (float)q8[5], qf6 = (float)q8[6], qf7 = (float)q8[7];
    float den = 0.f;
    float a0 = 0.f, a1 = 0.f, a2 = 0.f, a3 = 0.f;
    float a4 = 0.f, a5 = 0.f, a6 = 0.f, a7 = 0.f;
    int lane_off = lam * 16;

    auto edge = [&](uint4 kv, bool ok) {
        f32x2 k0 = __builtin_amdgcn_cvt_pk_f32_fp8((int)kv.x, false);
        f32x2 k1 = __builtin_amdgcn_cvt_pk_f32_fp8((int)kv.y, false);
        f32x2 k2 = __builtin_amdgcn_cvt_pk_f32_fp8((int)kv.z, false);
        f32x2 k3 = __builtin_amdgcn_cvt_pk_f32_fp8((int)kv.w, false);
        float p = k0.x * qf0 + k0.y * qf1 + k1.x * qf2 + k1.y * qf3
                + k2.x * qf4 + k2.y * qf5 + k3.x * qf6 + k3.y * qf7;
        p += __shfl_xor(p, 1, 64);         // head dot over lane pair (16 ch)
        float w = __expf(ok ? p : -1e30f);
        den += w;
        f32x2 v0 = __builtin_amdgcn_cvt_pk_f32_fp8((int)kv.x, true);
        f32x2 v1 = __builtin_amdgcn_cvt_pk_f32_fp8((int)kv.y, true);
        f32x2 v2 = __builtin_amdgcn_cvt_pk_f32_fp8((int)kv.z, true);
        f32x2 v3 = __builtin_amdgcn_cvt_pk_f32_fp8((int)kv.w, true);
        a0 = fmaf(w, v0.x, a0); a1 = fmaf(w, v0.y, a1);
        a2 = fmaf(w, v1.x, a2); a3 = fmaf(w, v1.y, a3);
        a4 = fmaf(w, v2.x, a4); a5 = fmaf(w, v2.y, a5);
        a6 = fmaf(w, v3.x, a6); a7 = fmaf(w, v3.y, a7);
    };

    int i0 = indptr[node], deg = indptr[node + 1] - i0;
    for (int base = 0; base < deg; base += 64) {
        int cnt = min(64, deg - base);
        int sv8 = 0;
        if (base + l < deg) sv8 = ((int)srcs[i0 + base + l]) << 8;  // kv row byte offset
        int e = 0;
        for (; e + 8 <= cnt; e += 8) {     // 2 loads (8 edges) in flight
            int oA = __shfl(sv8, e + quarter, 64);
            int oB = __shfl(sv8, e + 4 + quarter, 64);
            uint4 kvA = *(const uint4*)(kvbuf + oA + lane_off);
            uint4 kvB = *(const uint4*)(kvbuf + oB + lane_off);
            edge(kvA, true); edge(kvB, true);
        }
        for (; e < cnt; e += 4) {          // masked tail quads
            int idx = e + quarter;
            int o = __shfl(sv8, idx, 64);
            uint4 kv = *(const uint4*)(kvbuf + o + lane_off);
            edge(kv, idx < cnt);
        }
    }
    // merge quarter-wave partials
    den += __shfl_xor(den, 16, 64); den += __shfl_xor(den, 32, 64);
    a0 += __shfl_xor(a0, 16, 64); a0 += __shfl_xor(a0, 32, 64);
    a1 += __shfl_xor(a1, 16, 64); a1 += __shfl_xor(a1, 32, 64);
    a2 += __shfl_xor(a2, 16, 64); a2 += __shfl_xor(a2, 32, 64);
    a3 += __shfl_xor(a3, 16, 64); a3 += __shfl_xor(a3, 32, 64);
    a4 += __shfl_xor(a4, 16, 64); a4 += __shfl_xor(a4, 32, 64);
    a5 += __shfl_xor(a5, 16, 64); a5 += __shfl_xor(a5, 32, 64);
    a6 += __shfl_xor(a6, 16, 64); a6 += __shfl_xor(a6, 32, 64);
    a7 += __shfl_xor(a7, 16, 64); a7 += __shfl_xor(a7, 32, 64);
    if (quarter == 0) {
        float inv = 1.f / (den + 1e-16f);
        f16x8 s8 = ((const f16x8*)(nrow + 128))[lam];
        f16x8 o;
        o[0] = (_Float16)fmaf(a0, inv, (float)s8[0]);
        o[1] = (_Float16)fmaf(a1, inv, (float)s8[1]);
        o[2] = (_Float16)fmaf(a2, inv, (float)s8[2]);
        o[3] = (_Float16)fmaf(a3, inv, (float)s8[3]);
        o[4] = (_Float16)fmaf(a4, inv, (float)s8[4]);
        o[5] = (_Float16)fmaf(a5, inv, (float)s8[5]);
        o[6] = (_Float16)fmaf(a6, inv, (float)s8[6]);
        o[7] = (_Float16)fmaf(a7, inv, (float)s8[7]);
        ((f16x8*)(h1 + (size_t)node * 128))[lam] = o;
    }
}

// ---------------- gemm2: qkvs2[N,32] = h1[N,128] @ Wt2^T, f16 MFMA ----------------
__global__ __launch_bounds__(256) void gemm2(
    const _Float16* __restrict__ h1, const _Float16* __restrict__ Wt2,
    const float* __restrict__ b2, _Float16* __restrict__ qkvs2, int n)
{
    __shared__ _Float16 As[64][136];
    __shared__ _Float16 Bs[32][136];
    int tid = threadIdx.x;
    int rowbase = blockIdx.x * 64;
    #pragma unroll
    for (int it = 0; it < 4; ++it) {
        int c = it * 256 + tid, row = c >> 4, ch = c & 15;
        f16x8 v = {};
        if (rowbase + row < n) v = *(const f16x8*)&h1[(size_t)(rowbase + row) * 128 + ch * 8];
        *(f16x8*)&As[row][ch * 8] = v;
    }
    #pragma unroll
    for (int it = 0; it < 2; ++it) {
        int c = it * 256 + tid, row = c >> 4, ch = c & 15;
        *(f16x8*)&Bs[row][ch * 8] = *(const f16x8*)&Wt2[row * 128 + ch * 8];
    }
    __syncthreads();
    int w = tid >> 6, l = tid & 63, fr = l & 15, fg = l >> 4;
    f32x4 acc[2] = {};
    #pragma unroll
    for (int kk = 0; kk < 4; ++kk) {
        int ko = kk * 32 + fg * 8;
        f16x8 a = *(const f16x8*)&As[w * 16 + fr][ko];
        f16x8 b0 = *(const f16x8*)&Bs[fr][ko];
        f16x8 b1v = *(const f16x8*)&Bs[16 + fr][ko];
        acc[0] = __builtin_amdgcn_mfma_f32_16x16x32_f16(a, b0, acc[0], 0, 0, 0);
        acc[1] = __builtin_amdgcn_mfma_f32_16x16x32_f16(a, b1v, acc[1], 0, 0, 0);
    }
    #pragma unroll
    for (int nt = 0; nt < 2; ++nt) {
        int col = nt * 16 + fr;
        float bv = b2[col];
        #pragma unroll
        for (int r = 0; r < 4; ++r) {
            int row = rowbase + w * 16 + fg * 4 + r;
            if (row < n) qkvs2[(size_t)row * 32 + col] = (_Float16)(acc[nt][r] + bv);
        }
    }
}

// ---------------- attn2: wave/node, no-max online, packed kv dword gather ----------------
__global__ __launch_bounds__(256) void attn2(
    const _Float16* __restrict__ q2, const int* __restrict__ indptr,
    const unsigned short* __restrict__ srcs, float* __restrict__ h2, int n)
{
    int wid = threadIdx.x >> 6, l = threadIdx.x & 63;
    int node = blockIdx.x * 4 + wid;
    if (node >= n) return;
    int i = l >> 3, h = l & 7;
    const _Float16* base = q2 + (size_t)node * 32;
    float qh = (float)base[h];
    int i0 = indptr[node], i1 = indptr[node + 1];
    float den = 0.f, acc = 0.f;
    for (int p = i0 + i; p < i1; p += 8) {
        int s = srcs[p];
        f16x2 kv = ((const f16x2*)(q2 + (size_t)s * 32 + 8))[h];
        float w = __expf(qh * (float)kv.x);
        den += w;
        acc = fmaf(w, (float)kv.y, acc);
    }
    den += __shfl_xor(den, 8, 64); den += __shfl_xor(den, 16, 64); den += __shfl_xor(den, 32, 64);
    acc += __shfl_xor(acc, 8, 64); acc += __shfl_xor(acc, 16, 64); acc += __shfl_xor(acc, 32, 64);
    if (i == 0)
        h2[(size_t)node * 8 + h] = acc / (den + 1e-16f) + (float)base[24 + h];
}

// ---------------- final head ----------------
__global__ __launch_bounds__(128) void final_reduce(
    const float* __restrict__ h2, const float* __restrict__ Wl,
    const float* __restrict__ bl, float* __restrict__ out, int n, int chunk)
{
    int j = threadIdx.x;
    bool act = j < 100;
    float wl[8] = {};
    float bj = 0.f;
    if (act) {
        #pragma unroll
        for (int t = 0; t < 8; ++t) wl[t] = Wl[t * 100 + j];
        bj = bl[j];
    }
    int lo = blockIdx.x * chunk, hi = min(n, lo + chunk);
    float acc = 0.f;
    for (int node = lo; node < hi; ++node) {
        const float* hr = h2 + (size_t)node * 8;
        float y = bj;
        #pragma unroll
        for (int t = 0; t < 8; ++t) y += hr[t] * wl[t];
        acc += fmaxf(y, 0.f);
    }
    if (act) atomicAdd(&out[j], acc * (1.f / (float)n));
}

// ---------------- launch ----------------
extern "C" void kernel_launch(void* const* d_in, const int* in_sizes, int n_in,
                              void* d_out, int out_size, void* d_ws, size_t ws_size,
                              hipStream_t stream)
{
    const float* x   = (const float*)d_in[0];
    const int*   ei  = (const int*)d_in[1];
    const float* Wq1 = (const float*)d_in[2],  *bq1 = (const float*)d_in[3];
    const float* Wk1 = (const float*)d_in[4],  *bk1 = (const float*)d_in[5];
    const float* Wv1 = (const float*)d_in[6],  *bv1 = (const float*)d_in[7];
    const float* Ws1 = (const float*)d_in[8],  *bs1 = (const float*)d_in[9];
    const float* Wq2 = (const float*)d_in[10], *bq2 = (const float*)d_in[11];
    const float* Wk2 = (const float*)d_in[12], *bk2 = (const float*)d_in[13];
    const float* Wv2 = (const float*)d_in[14], *bv2 = (const float*)d_in[15];
    const float* Ws2 = (const float*)d_in[16], *bs2 = (const float*)d_in[17];
    const float* Wl  = (const float*)d_in[18], *bl  = (const float*)d_in[19];
    float* out = (float*)d_out;

    int n = in_sizes[0] / 128;     // 50000
    int E = in_sizes[1] / 2;       // 800000

    char* p = (char*)d_ws;
    auto take = [&](size_t bytes) -> void* {
        void* r = (void*)p;
        p += (bytes + 255) & ~(size_t)255;
        return r;
    };
    _Float16*       qs     = (_Float16*)take((size_t)n * 256 * 2);
    unsigned char*  kvbuf  = (unsigned char*)take((size_t)n * 256);
    _Float16*       h1     = (_Float16*)take((size_t)n * 128 * 2);
    _Float16*       qkvs2  = (_Float16*)take((size_t)n * 32 * 2);
    float*          h2     = (float*)take((size_t)n * 8 * 4);
    _Float16*       Wt1    = (_Float16*)take(65536 * 2);
    float*          b1     = (float*)take(512 * 4);
    _Float16*       Wt2    = (_Float16*)take(4096 * 2);
    float*          b2     = (float*)take(32 * 4);
    int*            counts = (int*)take((size_t)n * 4);
    int*            indptr = (int*)take((size_t)(n + 1) * 4);
    unsigned short* rank   = (unsigned short*)take((size_t)E * 2);
    unsigned short* srcs   = (unsigned short*)take((size_t)E * 2);

    pack_weights<<<(70400 + 255) / 256, 256, 0, stream>>>(
        Wq1, bq1, Wk1, bk1, Wv1, bv1, Ws1, bs1,
        Wq2, bq2, Wk2, bk2, Wv2, bv2, Ws2, bs2,
        Wt1, b1, Wt2, b2, counts, out, n, out_size);

    int eb = (E / 4 + 255) / 256;          // 4 edges per thread
    rank_edges<<<eb, 256, 0, stream>>>(ei, counts, rank, E);
    scan_all<<<1, 1024, 0, stream>>>(counts, indptr, n, E);
    place_edges<<<eb, 256, 0, stream>>>(ei, indptr, rank, srcs, E);

    gemm1<<<(n + 63) / 64, 256, 0, stream>>>(x, Wt1, b1, qs, kvbuf, n);
    attn1<<<(n + 3) / 4, 256, 0, stream>>>(qs, kvbuf, indptr, srcs, h1, n);
    gemm2<<<(n + 63) / 64, 256, 0, stream>>>(h1, Wt2, b2, qkvs2, n);
    attn2<<<(n + 3) / 4, 256, 0, stream>>>(qkvs2, indptr, srcs, h2, n);

    int chunk = (n + 255) / 256;
    final_reduce<<<256, 128, 0, stream>>>(h2, Wl, bl, out, n, chunk);
}

// Round 8
// 283.794 us; speedup vs baseline: 1.2363x; 1.2363x over previous
//
#include <hip/hip_runtime.h>
#include <hip/hip_bf16.h>
#include <cstdint>
#include <cstddef>

// Graph Transformer: 2x TransformerConv (H=8) + Linear(8,100) + mean over nodes.
// Round 8: scan_all rebuilt — register-resident int4 scan (13 independent 16B
// loads/thread, one latency exposure, prefix written from registers). counts
// padded +4096 zeros so vector loads are in-bounds. Everything else = R7.
// Layouts:
//   qs[N,256]    fp16: [ q(128, pre-scaled by 0.25) | s(128) ]
//   kvbuf[N,256] fp8 : [ (k2c,k2c+1,v2c,v2c+1) x64 ]   (256B gather row)
//   qkvs2[N,32]  fp16: [ q(8) | (k_h,v_h) x8 | s(8) ]

typedef _Float16 f16x8 __attribute__((ext_vector_type(8)));
typedef _Float16 f16x4 __attribute__((ext_vector_type(4)));
typedef _Float16 f16x2 __attribute__((ext_vector_type(2)));
typedef float    f32x4 __attribute__((ext_vector_type(4)));
typedef float    f32x2 __attribute__((ext_vector_type(2)));

#define SCAN_PAD 4096

// ---------------- weight packing + zero-init (counts incl. pad, out) ----------------
__global__ __launch_bounds__(256) void pack_weights(
    const float* __restrict__ Wq1, const float* __restrict__ bq1,
    const float* __restrict__ Wk1, const float* __restrict__ bk1,
    const float* __restrict__ Wv1, const float* __restrict__ bv1,
    const float* __restrict__ Ws1, const float* __restrict__ bs1,
    const float* __restrict__ Wq2, const float* __restrict__ bq2,
    const float* __restrict__ Wk2, const float* __restrict__ bk2,
    const float* __restrict__ Wv2, const float* __restrict__ bv2,
    const float* __restrict__ Ws2, const float* __restrict__ bs2,
    _Float16* __restrict__ Wt1, float* __restrict__ b1,
    _Float16* __restrict__ Wt2, float* __restrict__ b2,
    int* __restrict__ counts, float* __restrict__ out, int n, int out_size)
{
    int i = blockIdx.x * 256 + threadIdx.x;
    if (i < n + SCAN_PAD) counts[i] = 0;
    if (i < out_size) out[i] = 0.f;
    if (i < 65536) {                       // Wt1[j][k]
        int j = i >> 7, k = i & 127;
        const float* W; int col; float sc = 1.f;
        if (j < 128)      { W = Wq1; col = j; sc = 0.25f; }   // fold 1/sqrt(16)
        else if (j < 384) { int t = j - 128, c = t >> 2, r = t & 3;
                            if (r < 2) { W = Wk1; col = 2 * c + r; }
                            else       { W = Wv1; col = 2 * c + r - 2; } }
        else              { W = Ws1; col = j - 384; }
        Wt1[i] = (_Float16)(W[k * 128 + col] * sc);
    } else if (i < 66048) {
        int j = i - 65536;
        const float* B; int col; float sc = 1.f;
        if (j < 128)      { B = bq1; col = j; sc = 0.25f; }
        else if (j < 384) { int t = j - 128, c = t >> 2, r = t & 3;
                            if (r < 2) { B = bk1; col = 2 * c + r; }
                            else       { B = bv1; col = 2 * c + r - 2; } }
        else              { B = bs1; col = j - 384; }
        b1[j] = B[col] * sc;
    } else if (i < 66048 + 4096) {         // Wt2[j][k]
        int t = i - 66048;
        int j = t >> 7, k = t & 127;
        const float* W; int col;
        if (j < 8)       { W = Wq2; col = j; }
        else if (j < 24) { int u = j - 8; col = u >> 1; W = (u & 1) ? Wv2 : Wk2; }
        else             { W = Ws2; col = j - 24; }
        Wt2[t] = (_Float16)W[k * 8 + col];
    } else if (i < 66048 + 4096 + 32) {
        int j = i - (66048 + 4096);
        const float* B; int col;
        if (j < 8)       { B = bq2; col = j; }
        else if (j < 24) { int u = j - 8; col = u >> 1; B = (u & 1) ? bv2 : bk2; }
        else             { B = bs2; col = j - 24; }
        b2[j] = B[col];
    }
}

// ---------------- rank_edges: count + per-edge rank (4 edges/thread) ----------------
__global__ __launch_bounds__(256) void rank_edges(
    const int* __restrict__ ei, int* __restrict__ counts,
    unsigned short* __restrict__ rank, int E)
{
    int e0 = (blockIdx.x * 256 + threadIdx.x) * 4;
    if (e0 + 4 <= E) {
        int4 d4 = *(const int4*)&ei[E + e0];
        int r0 = atomicAdd(&counts[d4.x], 1);
        int r1 = atomicAdd(&counts[d4.y], 1);
        int r2 = atomicAdd(&counts[d4.z], 1);
        int r3 = atomicAdd(&counts[d4.w], 1);
        ushort4 rr = make_ushort4((unsigned short)r0, (unsigned short)r1,
                                  (unsigned short)r2, (unsigned short)r3);
        *(ushort4*)&rank[e0] = rr;
    } else {
        for (int e = e0; e < E; ++e)
            rank[e] = (unsigned short)atomicAdd(&counts[ei[E + e]], 1);
    }
}

// ---------------- scan_all: single-block, register-resident int4 scan ----------------
// 1024 threads x 52 elements (13 int4). All loads independent (one latency
// exposure); prefix computed and stored from registers (no re-read chain).
__global__ __launch_bounds__(1024) void scan_all(
    const int* __restrict__ counts, int* __restrict__ indptr, int n, int E)
{
    int t = threadIdx.x, lane = t & 63;
    int lo = t * 52;
    int4 c[13];
    #pragma unroll
    for (int j = 0; j < 13; ++j) c[j] = *(const int4*)&counts[lo + j * 4];  // padded
    int s = 0;
    #pragma unroll
    for (int j = 0; j < 13; ++j) s += c[j].x + c[j].y + c[j].z + c[j].w;
    int x = s;
    #pragma unroll
    for (int off = 1; off < 64; off <<= 1) {
        int y = __shfl_up(x, off, 64);
        if (lane >= off) x += y;
    }
    __shared__ int ws[16];
    if (lane == 63) ws[t >> 6] = x;
    __syncthreads();
    int woff = 0;
    #pragma unroll
    for (int w = 0; w < 15; ++w) if (w < (t >> 6)) woff += ws[w];
    int run = woff + x - s;                // exclusive base of this thread's chunk
    #pragma unroll
    for (int j = 0; j < 13; ++j) {
        int i = lo + j * 4;
        int4 v = c[j];
        int p0 = run, p1 = p0 + v.x, p2 = p1 + v.y, p3 = p2 + v.z;
        run = p3 + v.w;
        if (i + 3 < n) {
            *(int4*)&indptr[i] = make_int4(p0, p1, p2, p3);
        } else {
            if (i < n)     indptr[i]     = p0;
            if (i + 1 < n) indptr[i + 1] = p1;
            if (i + 2 < n) indptr[i + 2] = p2;
            if (i + 3 < n) indptr[i + 3] = p3;
        }
    }
    if (t == 0) indptr[n] = E;
}

// ---------------- place_edges: atomic-free scatter (u16 srcs) ----------------
__global__ __launch_bounds__(256) void place_edges(
    const int* __restrict__ ei, const int* __restrict__ indptr,
    const unsigned short* __restrict__ rank, unsigned short* __restrict__ srcs, int E)
{
    int e0 = (blockIdx.x * 256 + threadIdx.x) * 4;
    if (e0 + 4 <= E) {
        int4 s4 = *(const int4*)&ei[e0];
        int4 d4 = *(const int4*)&ei[E + e0];
        ushort4 r4 = *(const ushort4*)&rank[e0];
        srcs[indptr[d4.x] + r4.x] = (unsigned short)s4.x;
        srcs[indptr[d4.y] + r4.y] = (unsigned short)s4.y;
        srcs[indptr[d4.z] + r4.z] = (unsigned short)s4.z;
        srcs[indptr[d4.w] + r4.w] = (unsigned short)s4.w;
    } else {
        for (int e = e0; e < E; ++e)
            srcs[indptr[ei[E + e]] + rank[e]] = (unsigned short)ei[e];
    }
}

// ---------------- gemm1: col-loop, A staged once, Bs/Ds LDS union ----------------
__global__ __launch_bounds__(256) void gemm1(
    const float* __restrict__ x, const _Float16* __restrict__ Wt1,
    const float* __restrict__ b1, _Float16* __restrict__ qs,
    unsigned char* __restrict__ kvbuf, int n)
{
    __shared__ _Float16 As[64][136];
    __shared__ _Float16 BD[64][136];   // Bs during MFMA, Ds during epilogue
    int tid = threadIdx.x;
    int rowbase = blockIdx.x * 64;
    #pragma unroll
    for (int it = 0; it < 8; ++it) {   // A: fp32 load + convert, 64x128
        int c = it * 256 + tid, row = c >> 5, ch = c & 31;
        float4 v = make_float4(0.f, 0.f, 0.f, 0.f);
        if (rowbase + row < n) v = *(const float4*)&x[(size_t)(rowbase + row) * 128 + ch * 4];
        f16x4 hv = { (_Float16)v.x, (_Float16)v.y, (_Float16)v.z, (_Float16)v.w };
        *(f16x4*)&As[row][ch * 4] = hv;
    }
    int w = tid >> 6, l = tid & 63;
    int wm = w >> 1, wn = w & 1, fr = l & 15, fg = l >> 4;
    for (int cb = 0; cb < 8; ++cb) {
        __syncthreads();               // As ready / previous Ds consumed
        #pragma unroll
        for (int it = 0; it < 4; ++it) {
            int c = it * 256 + tid, row = c >> 4, ch = c & 15;
            *(f16x8*)&BD[row][ch * 8] =
                *(const f16x8*)&Wt1[(size_t)(cb * 64 + row) * 128 + ch * 8];
        }
        __syncthreads();
        f32x4 acc[2][2] = {};
        #pragma unroll
        for (int kk = 0; kk < 4; ++kk) {
            int ko = kk * 32 + fg * 8;
            f16x8 a0 = *(const f16x8*)&As[wm * 32 + fr][ko];
            f16x8 a1 = *(const f16x8*)&As[wm * 32 + 16 + fr][ko];
            f16x8 b0 = *(const f16x8*)&BD[wn * 32 + fr][ko];
            f16x8 b1v = *(const f16x8*)&BD[wn * 32 + 16 + fr][ko];
            acc[0][0] = __builtin_amdgcn_mfma_f32_16x16x32_f16(a0, b0, acc[0][0], 0, 0, 0);
            acc[0][1] = __builtin_amdgcn_mfma_f32_16x16x32_f16(a0, b1v, acc[0][1], 0, 0, 0);
            acc[1][0] = __builtin_amdgcn_mfma_f32_16x16x32_f16(a1, b0, acc[1][0], 0, 0, 0);
            acc[1][1] = __builtin_amdgcn_mfma_f32_16x16x32_f16(a1, b1v, acc[1][1], 0, 0, 0);
        }
        __syncthreads();               // Bs reads done; BD becomes Ds
        #pragma unroll
        for (int nt = 0; nt < 2; ++nt) {   // C/D: col=lane&15, row=(lane>>4)*4+r (m89)
            int col = wn * 32 + nt * 16 + fr;
            float bv = b1[cb * 64 + col];
            #pragma unroll
            for (int mt = 0; mt < 2; ++mt)
                #pragma unroll
                for (int r = 0; r < 4; ++r)
                    BD[wm * 32 + mt * 16 + fg * 4 + r][col] = (_Float16)(acc[mt][nt][r] + bv);
        }
        __syncthreads();
        if (cb >= 2 && cb < 6) {       // kv cols -> fp8 pack, 64 rows x 64 bytes
            int row = tid >> 2, ch = tid & 3;
            if (rowbase + row < n) {
                f16x8 d0 = *(const f16x8*)&BD[row][ch * 16];
                f16x8 d1 = *(const f16x8*)&BD[row][ch * 16 + 8];
                int w0 = 0, w1 = 0, w2 = 0, w3 = 0;
                w0 = __builtin_amdgcn_cvt_pk_fp8_f32((float)d0[0], (float)d0[1], w0, false);
                w0 = __builtin_amdgcn_cvt_pk_fp8_f32((float)d0[2], (float)d0[3], w0, true);
                w1 = __builtin_amdgcn_cvt_pk_fp8_f32((float)d0[4], (float)d0[5], w1, false);
                w1 = __builtin_amdgcn_cvt_pk_fp8_f32((float)d0[6], (float)d0[7], w1, true);
                w2 = __builtin_amdgcn_cvt_pk_fp8_f32((float)d1[0], (float)d1[1], w2, false);
                w2 = __builtin_amdgcn_cvt_pk_fp8_f32((float)d1[2], (float)d1[3], w2, true);
                w3 = __builtin_amdgcn_cvt_pk_fp8_f32((float)d1[4], (float)d1[5], w3, false);
                w3 = __builtin_amdgcn_cvt_pk_fp8_f32((float)d1[6], (float)d1[7], w3, true);
                uint4 o = make_uint4((unsigned)w0, (unsigned)w1, (unsigned)w2, (unsigned)w3);
                *(uint4*)&kvbuf[(size_t)(rowbase + row) * 256 + (cb - 2) * 64 + ch * 16] = o;
            }
        } else {                       // q / s cols -> qs fp16
            int dcol = (cb < 2) ? cb * 64 : (cb - 6) * 64 + 128;
            #pragma unroll
            for (int it = 0; it < 2; ++it) {
                int c = it * 256 + tid, row = c >> 3, ch = c & 7;
                if (rowbase + row < n)
                    *(f16x8*)&qs[(size_t)(rowbase + row) * 256 + dcol + ch * 8] =
                        *(const f16x8*)&BD[row][ch * 8];
            }
        }
    }
}

// ---------------- attn1: quarter-wave per edge, fp8 kv, no-max softmax ----------------
__global__ __launch_bounds__(256) void attn1(
    const _Float16* __restrict__ qs, const unsigned char* __restrict__ kvbuf,
    const int* __restrict__ indptr, const unsigned short* __restrict__ srcs,
    _Float16* __restrict__ h1, int n)
{
    int wid = threadIdx.x >> 6, l = threadIdx.x & 63;
    int node = blockIdx.x * 4 + wid;
    if (node >= n) return;
    int lam = l & 15, quarter = l >> 4;
    const _Float16* nrow = qs + (size_t)node * 256;
    f16x8 q8 = ((const f16x8*)nrow)[lam];
    float qf0 = (float)q8[0], qf1 = (float)q8[1], qf2 = (float)q8[2], qf3 = (float)q8[3];
    float qf4 = (float)q8[4], qf5 = (float)q8[5], qf6 = (float)q8[6], qf7 = (float)q8[7];
    float den = 0.f;
    float a0 = 0.f, a1 = 0.f, a2 = 0.f, a3 = 0.f;
    float a4 = 0.f, a5 = 0.f, a6 = 0.f, a7 = 0.f;
    int lane_off = lam * 16;

    auto edge = [&](uint4 kv, bool ok) {
        f32x2 k0 = __builtin_amdgcn_cvt_pk_f32_fp8((int)kv.x, false);
        f32x2 k1 = __builtin_amdgcn_cvt_pk_f32_fp8((int)kv.y, false);
        f32x2 k2 = __builtin_amdgcn_cvt_pk_f32_fp8((int)kv.z, false);
        f32x2 k3 = __builtin_amdgcn_cvt_pk_f32_fp8((int)kv.w, false);
        float p = k0.x * qf0 + k0.y * qf1 + k1.x * qf2 + k1.y * qf3
                + k2.x * qf4 + k2.y * qf5 + k3.x * qf6 + k3.y * qf7;
        p += __shfl_xor(p, 1, 64);         // head dot over lane pair (16 ch)
        float w = __expf(ok ? p : -1e30f);
        den += w;
        f32x2 v0 = __builtin_amdgcn_cvt_pk_f32_fp8((int)kv.x, true);
        f32x2 v1 = __builtin_amdgcn_cvt_pk_f32_fp8((int)kv.y, true);
        f32x2 v2 = __builtin_amdgcn_cvt_pk_f32_fp8((int)kv.z, true);
        f32x2 v3 = __builtin_amdgcn_cvt_pk_f32_fp8((int)kv.w, true);
        a0 = fmaf(w, v0.x, a0); a1 = fmaf(w, v0.y, a1);
        a2 = fmaf(w, v1.x, a2); a3 = fmaf(w, v1.y, a3);
        a4 = fmaf(w, v2.x, a4); a5 = fmaf(w, v2.y, a5);
        a6 = fmaf(w, v3.x, a6); a7 = fmaf(w, v3.y, a7);
    };

    int i0 = indptr[node], deg = indptr[node + 1] - i0;
    for (int base = 0; base < deg; base += 64) {
        int cnt = min(64, deg - base);
        int sv8 = 0;
        if (base + l < deg) sv8 = ((int)srcs[i0 + base + l]) << 8;  // kv row byte offset
        int e = 0;
        for (; e + 8 <= cnt; e += 8) {     // 2 loads (8 edges) in flight
            int oA = __shfl(sv8, e + quarter, 64);
            int oB = __shfl(sv8, e + 4 + quarter, 64);
            uint4 kvA = *(const uint4*)(kvbuf + oA + lane_off);
            uint4 kvB = *(const uint4*)(kvbuf + oB + lane_off);
            edge(kvA, true); edge(kvB, true);
        }
        for (; e < cnt; e += 4) {          // masked tail quads
            int idx = e + quarter;
            int o = __shfl(sv8, idx, 64);
            uint4 kv = *(const uint4*)(kvbuf + o + lane_off);
            edge(kv, idx < cnt);
        }
    }
    // merge quarter-wave partials
    den += __shfl_xor(den, 16, 64); den += __shfl_xor(den, 32, 64);
    a0 += __shfl_xor(a0, 16, 64); a0 += __shfl_xor(a0, 32, 64);
    a1 += __shfl_xor(a1, 16, 64); a1 += __shfl_xor(a1, 32, 64);
    a2 += __shfl_xor(a2, 16, 64); a2 += __shfl_xor(a2, 32, 64);
    a3 += __shfl_xor(a3, 16, 64); a3 += __shfl_xor(a3, 32, 64);
    a4 += __shfl_xor(a4, 16, 64); a4 += __shfl_xor(a4, 32, 64);
    a5 += __shfl_xor(a5, 16, 64); a5 += __shfl_xor(a5, 32, 64);
    a6 += __shfl_xor(a6, 16, 64); a6 += __shfl_xor(a6, 32, 64);
    a7 += __shfl_xor(a7, 16, 64); a7 += __shfl_xor(a7, 32, 64);
    if (quarter == 0) {
        float inv = 1.f / (den + 1e-16f);
        f16x8 s8 = ((const f16x8*)(nrow + 128))[lam];
        f16x8 o;
        o[0] = (_Float16)fmaf(a0, inv, (float)s8[0]);
        o[1] = (_Float16)fmaf(a1, inv, (float)s8[1]);
        o[2] = (_Float16)fmaf(a2, inv, (float)s8[2]);
        o[3] = (_Float16)fmaf(a3, inv, (float)s8[3]);
        o[4] = (_Float16)fmaf(a4, inv, (float)s8[4]);
        o[5] = (_Float16)fmaf(a5, inv, (float)s8[5]);
        o[6] = (_Float16)fmaf(a6, inv, (float)s8[6]);
        o[7] = (_Float16)fmaf(a7, inv, (float)s8[7]);
        ((f16x8*)(h1 + (size_t)node * 128))[lam] = o;
    }
}

// ---------------- gemm2: qkvs2[N,32] = h1[N,128] @ Wt2^T, f16 MFMA ----------------
__global__ __launch_bounds__(256) void gemm2(
    const _Float16* __restrict__ h1, const _Float16* __restrict__ Wt2,
    const float* __restrict__ b2, _Float16* __restrict__ qkvs2, int n)
{
    __shared__ _Float16 As[64][136];
    __shared__ _Float16 Bs[32][136];
    int tid = threadIdx.x;
    int rowbase = blockIdx.x * 64;
    #pragma unroll
    for (int it = 0; it < 4; ++it) {
        int c = it * 256 + tid, row = c >> 4, ch = c & 15;
        f16x8 v = {};
        if (rowbase + row < n) v = *(const f16x8*)&h1[(size_t)(rowbase + row) * 128 + ch * 8];
        *(f16x8*)&As[row][ch * 8] = v;
    }
    #pragma unroll
    for (int it = 0; it < 2; ++it) {
        int c = it * 256 + tid, row = c >> 4, ch = c & 15;
        *(f16x8*)&Bs[row][ch * 8] = *(const f16x8*)&Wt2[row * 128 + ch * 8];
    }
    __syncthreads();
    int w = tid >> 6, l = tid & 63, fr = l & 15, fg = l >> 4;
    f32x4 acc[2] = {};
    #pragma unroll
    for (int kk = 0; kk < 4; ++kk) {
        int ko = kk * 32 + fg * 8;
        f16x8 a = *(const f16x8*)&As[w * 16 + fr][ko];
        f16x8 b0 = *(const f16x8*)&Bs[fr][ko];
        f16x8 b1v = *(const f16x8*)&Bs[16 + fr][ko];
        acc[0] = __builtin_amdgcn_mfma_f32_16x16x32_f16(a, b0, acc[0], 0, 0, 0);
        acc[1] = __builtin_amdgcn_mfma_f32_16x16x32_f16(a, b1v, acc[1], 0, 0, 0);
    }
    #pragma unroll
    for (int nt = 0; nt < 2; ++nt) {
        int col = nt * 16 + fr;
        float bv = b2[col];
        #pragma unroll
        for (int r = 0; r < 4; ++r) {
            int row = rowbase + w * 16 + fg * 4 + r;
            if (row < n) qkvs2[(size_t)row * 32 + col] = (_Float16)(acc[nt][r] + bv);
        }
    }
}

// ---------------- attn2: wave/node, no-max online, packed kv dword gather ----------------
__global__ __launch_bounds__(256) void attn2(
    const _Float16* __restrict__ q2, const int* __restrict__ indptr,
    const unsigned short* __restrict__ srcs, float* __restrict__ h2, int n)
{
    int wid = threadIdx.x >> 6, l = threadIdx.x & 63;
    int node = blockIdx.x * 4 + wid;
    if (node >= n) return;
    int i = l >> 3, h = l & 7;
    const _Float16* base = q2 + (size_t)node * 32;
    float qh = (float)base[h];
    int i0 = indptr[node], i1 = indptr[node + 1];
    float den = 0.f, acc = 0.f;
    for (int p = i0 + i; p < i1; p += 8) {
        int s = srcs[p];
        f16x2 kv = ((const f16x2*)(q2 + (size_t)s * 32 + 8))[h];
        float w = __expf(qh * (float)kv.x);
        den += w;
        acc = fmaf(w, (float)kv.y, acc);
    }
    den += __shfl_xor(den, 8, 64); den += __shfl_xor(den, 16, 64); den += __shfl_xor(den, 32, 64);
    acc += __shfl_xor(acc, 8, 64); acc += __shfl_xor(acc, 16, 64); acc += __shfl_xor(acc, 32, 64);
    if (i == 0)
        h2[(size_t)node * 8 + h] = acc / (den + 1e-16f) + (float)base[24 + h];
}

// ---------------- final head ----------------
__global__ __launch_bounds__(128) void final_reduce(
    const float* __restrict__ h2, const float* __restrict__ Wl,
    const float* __restrict__ bl, float* __restrict__ out, int n, int chunk)
{
    int j = threadIdx.x;
    bool act = j < 100;
    float wl[8] = {};
    float bj = 0.f;
    if (act) {
        #pragma unroll
        for (int t = 0; t < 8; ++t) wl[t] = Wl[t * 100 + j];
        bj = bl[j];
    }
    int lo = blockIdx.x * chunk, hi = min(n, lo + chunk);
    float acc = 0.f;
    for (int node = lo; node < hi; ++node) {
        const float* hr = h2 + (size_t)node * 8;
        float y = bj;
        #pragma unroll
        for (int t = 0; t < 8; ++t) y += hr[t] * wl[t];
        acc += fmaxf(y, 0.f);
    }
    if (act) atomicAdd(&out[j], acc * (1.f / (float)n));
}

// ---------------- launch ----------------
extern "C" void kernel_launch(void* const* d_in, const int* in_sizes, int n_in,
                              void* d_out, int out_size, void* d_ws, size_t ws_size,
                              hipStream_t stream)
{
    const float* x   = (const float*)d_in[0];
    const int*   ei  = (const int*)d_in[1];
    const float* Wq1 = (const float*)d_in[2],  *bq1 = (const float*)d_in[3];
    const float* Wk1 = (const float*)d_in[4],  *bk1 = (const float*)d_in[5];
    const float* Wv1 = (const float*)d_in[6],  *bv1 = (const float*)d_in[7];
    const float* Ws1 = (const float*)d_in[8],  *bs1 = (const float*)d_in[9];
    const float* Wq2 = (const float*)d_in[10], *bq2 = (const float*)d_in[11];
    const float* Wk2 = (const float*)d_in[12], *bk2 = (const float*)d_in[13];
    const float* Wv2 = (const float*)d_in[14], *bv2 = (const float*)d_in[15];
    const float* Ws2 = (const float*)d_in[16], *bs2 = (const float*)d_in[17];
    const float* Wl  = (const float*)d_in[18], *bl  = (const float*)d_in[19];
    float* out = (float*)d_out;

    int n = in_sizes[0] / 128;     // 50000
    int E = in_sizes[1] / 2;       // 800000

    char* p = (char*)d_ws;
    auto take = [&](size_t bytes) -> void* {
        void* r = (void*)p;
        p += (bytes + 255) & ~(size_t)255;
        return r;
    };
    _Float16*       qs     = (_Float16*)take((size_t)n * 256 * 2);
    unsigned char*  kvbuf  = (unsigned char*)take((size_t)n * 256);
    _Float16*       h1     = (_Float16*)take((size_t)n * 128 * 2);
    _Float16*       qkvs2  = (_Float16*)take((size_t)n * 32 * 2);
    float*          h2     = (float*)take((size_t)n * 8 * 4);
    _Float16*       Wt1    = (_Float16*)take(65536 * 2);
    float*          b1     = (float*)take(512 * 4);
    _Float16*       Wt2    = (_Float16*)take(4096 * 2);
    float*          b2     = (float*)take(32 * 4);
    int*            counts = (int*)take((size_t)(n + SCAN_PAD) * 4);
    int*            indptr = (int*)take((size_t)(n + 1) * 4);
    unsigned short* rank   = (unsigned short*)take((size_t)E * 2);
    unsigned short* srcs   = (unsigned short*)take((size_t)E * 2);

    pack_weights<<<(70400 + 255) / 256, 256, 0, stream>>>(
        Wq1, bq1, Wk1, bk1, Wv1, bv1, Ws1, bs1,
        Wq2, bq2, Wk2, bk2, Wv2, bv2, Ws2, bs2,
        Wt1, b1, Wt2, b2, counts, out, n, out_size);

    int eb = (E / 4 + 255) / 256;          // 4 edges per thread
    rank_edges<<<eb, 256, 0, stream>>>(ei, counts, rank, E);
    scan_all<<<1, 1024, 0, stream>>>(counts, indptr, n, E);
    place_edges<<<eb, 256, 0, stream>>>(ei, indptr, rank, srcs, E);

    gemm1<<<(n + 63) / 64, 256, 0, stream>>>(x, Wt1, b1, qs, kvbuf, n);
    attn1<<<(n + 3) / 4, 256, 0, stream>>>(qs, kvbuf, indptr, srcs, h1, n);
    gemm2<<<(n + 63) / 64, 256, 0, stream>>>(h1, Wt2, b2, qkvs2, n);
    attn2<<<(n + 3) / 4, 256, 0, stream>>>(qkvs2, indptr, srcs, h2, n);

    int chunk = (n + 255) / 256;
    final_reduce<<<256, 128, 0, stream>>>(h2, Wl, bl, out, n, chunk);
}